// Round 4
// baseline (460.637 us; speedup 1.0000x reference)
//
#include <hip/hip_runtime.h>
#include <hip/hip_bf16.h>
#include <math.h>

#define HN 39
#define WN 39
#define NBATCH 128
#define NPIX (HN * WN)          // 1521
#define NNODE (NBATCH * WN)     // 4992
#define E_RAW 200064
#define E_TOT (E_RAW + NNODE)   // 205056
#define F1 512
#define F2 64

static __device__ __forceinline__ float nan0(float x) { return (x == x) ? x : 0.f; }
static __device__ __forceinline__ float sigmoid_f(float x) { return 1.f / (1.f + __expf(-x)); }
static __device__ __forceinline__ float tanh_f(float x) {
    float e = __expf(2.f * x);
    return 1.f - 2.f / (e + 1.f);   // robust: +/-inf -> +/-1
}

#define BN_RSQ 0.99999500003749969f   // 1/sqrt(1+1e-5)

// ---------------------------------------------------------------------------
// K1: fused nan-clean + conv1(1x1)+BN+ReLU + conv2(3x3)+BN + GRU input proj
// ---------------------------------------------------------------------------
__global__ __launch_bounds__(256) void conv_kernel(
    const float* __restrict__ ve, const float* __restrict__ ac, const float* __restrict__ man,
    const float* __restrict__ c1w, const float* __restrict__ c1b,
    const float* __restrict__ bn1g, const float* __restrict__ bn1b,
    const float* __restrict__ c2w, const float* __restrict__ c2b,
    const float* __restrict__ bn2g, const float* __restrict__ bn2b,
    const float* __restrict__ wih, const float* __restrict__ bih,
    float* __restrict__ gi_out)      // (B, 1521, 3)
{
    __shared__ float y1[8][NPIX + 7];
    const int b = blockIdx.x;
    const int tid = threadIdx.x;

    for (int p = tid; p < NPIX; p += 256) {
        float m = nan0(man[b * NPIX + p]);
        float a = nan0(ac[b * NPIX + p]);
        float v = nan0(ve[b * NPIX + p]);
#pragma unroll
        for (int c = 0; c < 8; ++c) {
            float val = c1w[c * 3 + 0] * m + c1w[c * 3 + 1] * a + c1w[c * 3 + 2] * v + c1b[c];
            val = val * (bn1g[c] * BN_RSQ) + bn1b[c];
            y1[c][p] = fmaxf(val, 0.f);
        }
    }
    __syncthreads();

    for (int p = tid; p < NPIX; p += 256) {
        const int h = p / WN, w = p - h * WN;
        float acc[16];
#pragma unroll
        for (int o = 0; o < 16; ++o) acc[o] = 0.f;
        for (int c = 0; c < 8; ++c) {
#pragma unroll
            for (int dy = 0; dy < 3; ++dy) {
                const int hh = h + dy - 1;
                if (hh < 0 || hh >= HN) continue;
#pragma unroll
                for (int dx = 0; dx < 3; ++dx) {
                    const int ww = w + dx - 1;
                    if (ww < 0 || ww >= WN) continue;
                    const float yv = y1[c][hh * WN + ww];
#pragma unroll
                    for (int o = 0; o < 16; ++o)
                        acc[o] = fmaf(c2w[((o * 8 + c) * 3 + dy) * 3 + dx], yv, acc[o]);
                }
            }
        }
        float gi0 = bih[0], gi1 = bih[1], gi2 = bih[2];
#pragma unroll
        for (int o = 0; o < 16; ++o) {
            const float x2 = (acc[o] + c2b[o]) * (bn2g[o] * BN_RSQ) + bn2b[o];
            gi0 = fmaf(wih[0 * 16 + o], x2, gi0);
            gi1 = fmaf(wih[1 * 16 + o], x2, gi1);
            gi2 = fmaf(wih[2 * 16 + o], x2, gi2);
        }
        const int idx = (b * NPIX + p) * 3;
        gi_out[idx + 0] = gi0;
        gi_out[idx + 1] = gi1;
        gi_out[idx + 2] = gi2;
    }
}

// ---------------------------------------------------------------------------
// K2: fused GRU(16->1) + xn build. One thread per (b,w) sequence; writes both
// halves of xn directly (saves enc1 round-trip + one launch).
// ---------------------------------------------------------------------------
__global__ __launch_bounds__(256) void gru_xn_kernel(
    const float* __restrict__ gi, const float* __restrict__ whh, const float* __restrict__ bhh,
    const float* __restrict__ man, const float* __restrict__ maskv,
    float* __restrict__ xn)   // (NNODE, 78)
{
    const int idx = blockIdx.x * 256 + threadIdx.x;
    if (idx >= NNODE) return;
    const int b = idx / WN, w = idx - (idx / WN) * WN;
    const float mk = maskv[idx];
    float* __restrict__ xrow = xn + (size_t)idx * 78;

    for (int k = 0; k < HN; ++k)
        xrow[k] = nan0(man[b * NPIX + k * WN + w]) * mk;

    const float wh0 = whh[0], wh1 = whh[1], wh2 = whh[2];
    const float bh0 = bhh[0], bh1 = bhh[1], bh2 = bhh[2];
    float h = 0.f;
    for (int t = 0; t < HN; ++t) {
        const float* g = gi + ((size_t)b * NPIX + t * WN + w) * 3;
        const float g0 = g[0], g1 = g[1], g2 = g[2];
        const float r = sigmoid_f(g0 + h * wh0 + bh0);
        const float z = sigmoid_f(g1 + h * wh1 + bh1);
        const float n = tanh_f(g2 + r * (h * wh2 + bh2));
        h = (1.f - z) * n + z * h;
        xrow[HN + t] = h * mk;
    }
}

// ---------------------------------------------------------------------------
// K4: CSR build (histogram -> scan -> scatter)
// ---------------------------------------------------------------------------
__global__ __launch_bounds__(256) void edge_hist(const int* __restrict__ ei, int* __restrict__ counts)
{
    const int e = blockIdx.x * 256 + threadIdx.x;
    if (e >= E_TOT) return;
    const int d = (e < E_RAW) ? ei[E_RAW + e] : (e - E_RAW);
    atomicAdd(&counts[d], 1);
}

__global__ __launch_bounds__(256) void scan_kernel(const int* __restrict__ counts,
                                                   int* __restrict__ offsets, int* __restrict__ cursor)
{
    __shared__ int sums[256];
    const int tid = threadIdx.x;
    const int start = tid * 20;
    const int end = min(start + 20, NNODE);
    int s = 0;
    for (int i = start; i < end; ++i) s += counts[i];
    sums[tid] = s;
    __syncthreads();
    for (int off = 1; off < 256; off <<= 1) {
        int v = (tid >= off) ? sums[tid - off] : 0;
        __syncthreads();
        sums[tid] += v;
        __syncthreads();
    }
    int run = (tid == 0) ? 0 : sums[tid - 1];
    for (int i = start; i < end; ++i) {
        offsets[i] = run;
        cursor[i] = run;
        run += counts[i];
    }
    if (tid == 255) offsets[NNODE] = run;
}

__global__ __launch_bounds__(256) void edge_scatter(const int* __restrict__ ei,
                                                    int* __restrict__ cursor, int* __restrict__ srcs)
{
    const int e = blockIdx.x * 256 + threadIdx.x;
    if (e >= E_TOT) return;
    int s, d;
    if (e < E_RAW) { s = ei[e]; d = ei[E_RAW + e]; }
    else           { s = d = e - E_RAW; }
    const int pos = atomicAdd(&cursor[d], 1);
    srcs[pos] = s;
}

// ---------------------------------------------------------------------------
// K5: tiled f32 GEMM  Y = X(M,K) @ W(J,K)^T + b, for both (Wl,Yl) and (Wr,Yr).
// Inner unroll capped at 8 (R1 fix: full unroll -> 256 VGPR + scratch spills).
// ---------------------------------------------------------------------------
template <int K>
__global__ __launch_bounds__(256, 4) void gemm_kernel(
    const float* __restrict__ X,
    const float* __restrict__ Wl, const float* __restrict__ bl,
    const float* __restrict__ Wr, const float* __restrict__ br,
    float* __restrict__ Yl, float* __restrict__ Yr, int J)
{
    const int nyb = J >> 6;
    const int sel = (blockIdx.y >= nyb) ? 1 : 0;
    const int j0 = (blockIdx.y - sel * nyb) * 64;
    const float* __restrict__ W = sel ? Wr : Wl;
    const float* __restrict__ bias = sel ? br : bl;
    float* __restrict__ Y = sel ? Yr : Yl;

    __shared__ __align__(16) float Xs[32][68];
    __shared__ __align__(16) float Ws[32][68];

    const int m0 = blockIdx.x * 64;
    const int tid = threadIdx.x;
    const int ti = tid / 16, tj = tid & 15;
    const int lrow = tid >> 2;            // 0..63
    const int ks = (tid & 3) * 8;         // 0,8,16,24

    float acc[4][4];
#pragma unroll
    for (int i = 0; i < 4; ++i)
#pragma unroll
        for (int j = 0; j < 4; ++j) acc[i][j] = 0.f;

    for (int k0 = 0; k0 < K; k0 += 32) {
        const float* xp = X + (size_t)(m0 + lrow) * K + k0 + ks;
        const float* wp = W + (size_t)(j0 + lrow) * K + k0 + ks;
#pragma unroll
        for (int q = 0; q < 8; ++q) {
            const int k = k0 + ks + q;
            Xs[ks + q][lrow] = (k < K) ? xp[q] : 0.f;
            Ws[ks + q][lrow] = (k < K) ? wp[q] : 0.f;
        }
        __syncthreads();
#pragma unroll 8
        for (int kk = 0; kk < 32; ++kk) {
            const float4 xv = *(const float4*)&Xs[kk][ti * 4];
            const float4 wv = *(const float4*)&Ws[kk][tj * 4];
            acc[0][0] = fmaf(xv.x, wv.x, acc[0][0]);
            acc[0][1] = fmaf(xv.x, wv.y, acc[0][1]);
            acc[0][2] = fmaf(xv.x, wv.z, acc[0][2]);
            acc[0][3] = fmaf(xv.x, wv.w, acc[0][3]);
            acc[1][0] = fmaf(xv.y, wv.x, acc[1][0]);
            acc[1][1] = fmaf(xv.y, wv.y, acc[1][1]);
            acc[1][2] = fmaf(xv.y, wv.z, acc[1][2]);
            acc[1][3] = fmaf(xv.y, wv.w, acc[1][3]);
            acc[2][0] = fmaf(xv.z, wv.x, acc[2][0]);
            acc[2][1] = fmaf(xv.z, wv.y, acc[2][1]);
            acc[2][2] = fmaf(xv.z, wv.z, acc[2][2]);
            acc[2][3] = fmaf(xv.z, wv.w, acc[2][3]);
            acc[3][0] = fmaf(xv.w, wv.x, acc[3][0]);
            acc[3][1] = fmaf(xv.w, wv.y, acc[3][1]);
            acc[3][2] = fmaf(xv.w, wv.z, acc[3][2]);
            acc[3][3] = fmaf(xv.w, wv.w, acc[3][3]);
        }
        __syncthreads();
    }
#pragma unroll
    for (int i = 0; i < 4; ++i) {
        const int m = m0 + ti * 4 + i;
#pragma unroll
        for (int j = 0; j < 4; ++j) {
            const int jj = j0 + tj * 4 + j;
            Y[(size_t)m * J + jj] = acc[i][j] + bias[jj];
        }
    }
}

// ---------------------------------------------------------------------------
// GATv2 core: chunked register-resident online softmax (R3 fix for the
// per-edge serial chain). 16 independent gathers + 16 independent shuffle
// reduces per chunk, ONE rescale per chunk, split accumulators for ILP.
// ---------------------------------------------------------------------------
template <int FDIM>
static __device__ __forceinline__ float gat_accum(
    const float* __restrict__ xl, const int* __restrict__ srcs,
    int base, int deg, int t, float xrv, float attv)
{
    const int lane = threadIdx.x & 63;
    float m = -1e30f, l = 0.f, acc = 0.f;

    for (int c0 = 0; c0 < deg; c0 += 16) {
        const int cnt = min(16, deg - c0);
        // lanes 0..15 hold the (up to) 16 src indices (replicated x4); clamp tail
        const int sv = srcs[base + c0 + min(lane & 15, cnt - 1)];

        float xlv[16], lg[16];
#pragma unroll
        for (int i = 0; i < 16; ++i) {
            const int si = __shfl(sv, i, 64);
            xlv[i] = xl[(size_t)si * FDIM + t];     // 16 independent gathers
        }
#pragma unroll
        for (int i = 0; i < 16; ++i) {
            float ev = xlv[i] + xrv;
            ev = (ev > 0.f) ? ev : 0.2f * ev;
            float p = ev * attv;
#pragma unroll
            for (int o = 32; o >= 1; o >>= 1) p += __shfl_xor(p, o, 64);
            lg[i] = (i < cnt) ? p : -1e30f;         // masked tail -> exp = 0
        }
        // chunk max (tree)
        const float a0 = fmaxf(fmaxf(fmaxf(lg[0], lg[1]), fmaxf(lg[2], lg[3])),
                               fmaxf(fmaxf(lg[4], lg[5]), fmaxf(lg[6], lg[7])));
        const float a1 = fmaxf(fmaxf(fmaxf(lg[8], lg[9]), fmaxf(lg[10], lg[11])),
                               fmaxf(fmaxf(lg[12], lg[13]), fmaxf(lg[14], lg[15])));
        const float m2 = fmaxf(m, fmaxf(a0, a1));
        const float sc = __expf(m - m2);
        l *= sc;
        acc *= sc;
        float l0 = 0.f, l1 = 0.f, s0 = 0.f, s1 = 0.f;
#pragma unroll
        for (int i = 0; i < 16; i += 2) {
            const float w0 = __expf(lg[i] - m2);
            const float w1 = __expf(lg[i + 1] - m2);
            l0 += w0;
            l1 += w1;
            s0 = fmaf(w0, xlv[i], s0);
            s1 = fmaf(w1, xlv[i + 1], s1);
        }
        l += l0 + l1;
        acc += s0 + s1;
        m = m2;
    }
    return acc / l;
}

// K6: GATv2 layer 1 (8 heads x 64ch). One block (512 thr) per dst node; wave = head.
__global__ __launch_bounds__(512) void gat1_kernel(
    const float* __restrict__ xl, const float* __restrict__ xr,
    const float* __restrict__ att, const float* __restrict__ bias,
    const int* __restrict__ offsets, const int* __restrict__ srcs,
    float* __restrict__ h1)
{
    const int n = blockIdx.x;
    const int t = threadIdx.x;
    const float xrv = xr[(size_t)n * F1 + t];
    const float attv = att[t];
    const int base = offsets[n];
    const int deg = offsets[n + 1] - base;

    float v = gat_accum<F1>(xl, srcs, base, deg, t, xrv, attv) + bias[t];
    v = (v > 0.f) ? v : expm1f(v);   // ELU
    h1[(size_t)n * F1 + t] = v;
}

// K7: GATv2 layer 2 (1 head x 64ch). One wave per dst node, 4 nodes/block.
__global__ __launch_bounds__(256) void gat2_kernel(
    const float* __restrict__ xl, const float* __restrict__ xr,
    const float* __restrict__ att, const float* __restrict__ bias,
    const int* __restrict__ offsets, const int* __restrict__ srcs,
    float* __restrict__ out)
{
    const int wave = threadIdx.x >> 6;
    const int lane = threadIdx.x & 63;
    const int n = blockIdx.x * 4 + wave;
    if (n >= NNODE) return;
    const float xrv = xr[(size_t)n * F2 + lane];
    const float attv = att[lane];
    const int base = offsets[n];
    const int deg = offsets[n + 1] - base;

    const float v = gat_accum<F2>(xl, srcs, base, deg, lane, xrv, attv);
    out[(size_t)n * F2 + lane] = v + bias[lane];
}

// ---------------------------------------------------------------------------
extern "C" void kernel_launch(void* const* d_in, const int* in_sizes, int n_in,
                              void* d_out, int out_size, void* d_ws, size_t ws_size,
                              hipStream_t stream)
{
    const int*   ei    = (const int*)d_in[0];
    const float* ve    = (const float*)d_in[1];
    const float* ac    = (const float*)d_in[2];
    const float* man   = (const float*)d_in[3];
    const float* maskv = (const float*)d_in[4];
    const float* c1w   = (const float*)d_in[6];
    const float* c1b   = (const float*)d_in[7];
    const float* bn1g  = (const float*)d_in[8];
    const float* bn1b  = (const float*)d_in[9];
    const float* c2w   = (const float*)d_in[10];
    const float* c2b   = (const float*)d_in[11];
    const float* bn2g  = (const float*)d_in[12];
    const float* bn2b  = (const float*)d_in[13];
    const float* wih   = (const float*)d_in[14];
    const float* whh   = (const float*)d_in[15];
    const float* bih   = (const float*)d_in[16];
    const float* bhh   = (const float*)d_in[17];
    const float* g1wl  = (const float*)d_in[18];
    const float* g1bl  = (const float*)d_in[19];
    const float* g1wr  = (const float*)d_in[20];
    const float* g1br  = (const float*)d_in[21];
    const float* g1att = (const float*)d_in[22];
    const float* g1bias= (const float*)d_in[23];
    const float* g2wl  = (const float*)d_in[24];
    const float* g2bl  = (const float*)d_in[25];
    const float* g2wr  = (const float*)d_in[26];
    const float* g2br  = (const float*)d_in[27];
    const float* g2att = (const float*)d_in[28];
    const float* g2bias= (const float*)d_in[29];
    float* outp = (float*)d_out;

    // workspace layout (floats)
    float* ws   = (float*)d_ws;
    float* gi   = ws;                       // 584064
    float* xn   = gi   + 584064;            // 389376
    float* xl1  = xn   + 389376;            // 2555904
    float* xr1  = xl1  + 2555904;           // 2555904
    float* h1   = xr1  + 2555904;           // 2555904
    float* xl2  = h1   + 2555904;           // 319488
    float* xr2  = xl2  + 319488;            // 319488
    int* counts  = (int*)(xr2 + 319488);    // 4992
    int* offsets = counts + NNODE;          // 4993
    int* cursor  = offsets + NNODE + 1;     // 4992
    int* srcs    = cursor + NNODE;          // 205056

    hipMemsetAsync(counts, 0, NNODE * sizeof(int), stream);

    conv_kernel<<<NBATCH, 256, 0, stream>>>(ve, ac, man, c1w, c1b, bn1g, bn1b,
                                            c2w, c2b, bn2g, bn2b, wih, bih, gi);
    gru_xn_kernel<<<(NNODE + 255) / 256, 256, 0, stream>>>(gi, whh, bhh, man, maskv, xn);

    edge_hist<<<(E_TOT + 255) / 256, 256, 0, stream>>>(ei, counts);
    scan_kernel<<<1, 256, 0, stream>>>(counts, offsets, cursor);
    edge_scatter<<<(E_TOT + 255) / 256, 256, 0, stream>>>(ei, cursor, srcs);

    gemm_kernel<78><<<dim3(NNODE / 64, 2 * (F1 / 64)), 256, 0, stream>>>(
        xn, g1wl, g1bl, g1wr, g1br, xl1, xr1, F1);

    gat1_kernel<<<NNODE, 512, 0, stream>>>(xl1, xr1, g1att, g1bias, offsets, srcs, h1);

    gemm_kernel<512><<<dim3(NNODE / 64, 2 * (F2 / 64)), 256, 0, stream>>>(
        h1, g2wl, g2bl, g2wr, g2br, xl2, xr2, F2);

    gat2_kernel<<<(NNODE + 3) / 4, 256, 0, stream>>>(xl2, xr2, g2att, g2bias, offsets, srcs, outp);
}

// Round 5
// 416.045 us; speedup vs baseline: 1.1072x; 1.1072x over previous
//
#include <hip/hip_runtime.h>
#include <hip/hip_bf16.h>
#include <math.h>

#define HN 39
#define WN 39
#define NBATCH 128
#define NPIX (HN * WN)          // 1521
#define NNODE (NBATCH * WN)     // 4992
#define E_RAW 200064
#define E_TOT (E_RAW + NNODE)   // 205056
#define NG4 (E_TOT / 4)         // 51264 edge-groups of 4
#define F1 512
#define F2 64
#define MAXDEG 256

static __device__ __forceinline__ float nan0(float x) { return (x == x) ? x : 0.f; }
static __device__ __forceinline__ float sigmoid_f(float x) { return 1.f / (1.f + __expf(-x)); }
static __device__ __forceinline__ float tanh_f(float x) {
    float e = __expf(2.f * x);
    return 1.f - 2.f / (e + 1.f);
}

#define BN_RSQ 0.99999500003749969f   // 1/sqrt(1+1e-5)

// ---------------------------------------------------------------------------
// K1: fused nan-clean + conv1(1x1)+BN+ReLU + conv2(3x3)+BN + GRU input proj
// ---------------------------------------------------------------------------
__global__ __launch_bounds__(256) void conv_kernel(
    const float* __restrict__ ve, const float* __restrict__ ac, const float* __restrict__ man,
    const float* __restrict__ c1w, const float* __restrict__ c1b,
    const float* __restrict__ bn1g, const float* __restrict__ bn1b,
    const float* __restrict__ c2w, const float* __restrict__ c2b,
    const float* __restrict__ bn2g, const float* __restrict__ bn2b,
    const float* __restrict__ wih, const float* __restrict__ bih,
    float* __restrict__ gi_out)      // (B, 1521, 3)
{
    __shared__ float y1[8][NPIX + 7];
    const int b = blockIdx.x;
    const int tid = threadIdx.x;

    for (int p = tid; p < NPIX; p += 256) {
        float m = nan0(man[b * NPIX + p]);
        float a = nan0(ac[b * NPIX + p]);
        float v = nan0(ve[b * NPIX + p]);
#pragma unroll
        for (int c = 0; c < 8; ++c) {
            float val = c1w[c * 3 + 0] * m + c1w[c * 3 + 1] * a + c1w[c * 3 + 2] * v + c1b[c];
            val = val * (bn1g[c] * BN_RSQ) + bn1b[c];
            y1[c][p] = fmaxf(val, 0.f);
        }
    }
    __syncthreads();

    for (int p = tid; p < NPIX; p += 256) {
        const int h = p / WN, w = p - h * WN;
        float acc[16];
#pragma unroll
        for (int o = 0; o < 16; ++o) acc[o] = 0.f;
        for (int c = 0; c < 8; ++c) {
#pragma unroll
            for (int dy = 0; dy < 3; ++dy) {
                const int hh = h + dy - 1;
                if (hh < 0 || hh >= HN) continue;
#pragma unroll
                for (int dx = 0; dx < 3; ++dx) {
                    const int ww = w + dx - 1;
                    if (ww < 0 || ww >= WN) continue;
                    const float yv = y1[c][hh * WN + ww];
#pragma unroll
                    for (int o = 0; o < 16; ++o)
                        acc[o] = fmaf(c2w[((o * 8 + c) * 3 + dy) * 3 + dx], yv, acc[o]);
                }
            }
        }
        float gi0 = bih[0], gi1 = bih[1], gi2 = bih[2];
#pragma unroll
        for (int o = 0; o < 16; ++o) {
            const float x2 = (acc[o] + c2b[o]) * (bn2g[o] * BN_RSQ) + bn2b[o];
            gi0 = fmaf(wih[0 * 16 + o], x2, gi0);
            gi1 = fmaf(wih[1 * 16 + o], x2, gi1);
            gi2 = fmaf(wih[2 * 16 + o], x2, gi2);
        }
        const int idx = (b * NPIX + p) * 3;
        gi_out[idx + 0] = gi0;
        gi_out[idx + 1] = gi1;
        gi_out[idx + 2] = gi2;
    }
}

// ---------------------------------------------------------------------------
// K2: fused GRU(16->1) + xn build
// ---------------------------------------------------------------------------
__global__ __launch_bounds__(256) void gru_xn_kernel(
    const float* __restrict__ gi, const float* __restrict__ whh, const float* __restrict__ bhh,
    const float* __restrict__ man, const float* __restrict__ maskv,
    float* __restrict__ xn)   // (NNODE, 78)
{
    const int idx = blockIdx.x * 256 + threadIdx.x;
    if (idx >= NNODE) return;
    const int b = idx / WN, w = idx - (idx / WN) * WN;
    const float mk = maskv[idx];
    float* __restrict__ xrow = xn + (size_t)idx * 78;

    for (int k = 0; k < HN; ++k)
        xrow[k] = nan0(man[b * NPIX + k * WN + w]) * mk;

    const float wh0 = whh[0], wh1 = whh[1], wh2 = whh[2];
    const float bh0 = bhh[0], bh1 = bhh[1], bh2 = bhh[2];
    float h = 0.f;
    for (int t = 0; t < HN; ++t) {
        const float* g = gi + ((size_t)b * NPIX + t * WN + w) * 3;
        const float g0 = g[0], g1 = g[1], g2 = g[2];
        const float r = sigmoid_f(g0 + h * wh0 + bh0);
        const float z = sigmoid_f(g1 + h * wh1 + bh1);
        const float n = tanh_f(g2 + r * (h * wh2 + bh2));
        h = (1.f - z) * n + z * h;
        xrow[HN + t] = h * mk;
    }
}

// ---------------------------------------------------------------------------
// K4: CSR build (histogram -> scan -> scatter); scatter also records dst
// ---------------------------------------------------------------------------
__global__ __launch_bounds__(256) void edge_hist(const int* __restrict__ ei, int* __restrict__ counts)
{
    const int e = blockIdx.x * 256 + threadIdx.x;
    if (e >= E_TOT) return;
    const int d = (e < E_RAW) ? ei[E_RAW + e] : (e - E_RAW);
    atomicAdd(&counts[d], 1);
}

__global__ __launch_bounds__(256) void scan_kernel(const int* __restrict__ counts,
                                                   int* __restrict__ offsets, int* __restrict__ cursor)
{
    __shared__ int sums[256];
    const int tid = threadIdx.x;
    const int start = tid * 20;
    const int end = min(start + 20, NNODE);
    int s = 0;
    for (int i = start; i < end; ++i) s += counts[i];
    sums[tid] = s;
    __syncthreads();
    for (int off = 1; off < 256; off <<= 1) {
        int v = (tid >= off) ? sums[tid - off] : 0;
        __syncthreads();
        sums[tid] += v;
        __syncthreads();
    }
    int run = (tid == 0) ? 0 : sums[tid - 1];
    for (int i = start; i < end; ++i) {
        offsets[i] = run;
        cursor[i] = run;
        run += counts[i];
    }
    if (tid == 255) offsets[NNODE] = run;
}

__global__ __launch_bounds__(256) void edge_scatter(const int* __restrict__ ei,
                                                    int* __restrict__ cursor,
                                                    int* __restrict__ srcs, int* __restrict__ dsts)
{
    const int e = blockIdx.x * 256 + threadIdx.x;
    if (e >= E_TOT) return;
    int s, d;
    if (e < E_RAW) { s = ei[e]; d = ei[E_RAW + e]; }
    else           { s = d = e - E_RAW; }
    const int pos = atomicAdd(&cursor[d], 1);
    srcs[pos] = s;
    dsts[pos] = d;
}

// ---------------------------------------------------------------------------
// K5: tiled f32 GEMM  Y = X(M,K) @ W(J,K)^T + b (unroll capped: R1 spill fix)
// ---------------------------------------------------------------------------
template <int K>
__global__ __launch_bounds__(256, 4) void gemm_kernel(
    const float* __restrict__ X,
    const float* __restrict__ Wl, const float* __restrict__ bl,
    const float* __restrict__ Wr, const float* __restrict__ br,
    float* __restrict__ Yl, float* __restrict__ Yr, int J)
{
    const int nyb = J >> 6;
    const int sel = (blockIdx.y >= nyb) ? 1 : 0;
    const int j0 = (blockIdx.y - sel * nyb) * 64;
    const float* __restrict__ W = sel ? Wr : Wl;
    const float* __restrict__ bias = sel ? br : bl;
    float* __restrict__ Y = sel ? Yr : Yl;

    __shared__ __align__(16) float Xs[32][68];
    __shared__ __align__(16) float Ws[32][68];

    const int m0 = blockIdx.x * 64;
    const int tid = threadIdx.x;
    const int ti = tid / 16, tj = tid & 15;
    const int lrow = tid >> 2;
    const int ks = (tid & 3) * 8;

    float acc[4][4];
#pragma unroll
    for (int i = 0; i < 4; ++i)
#pragma unroll
        for (int j = 0; j < 4; ++j) acc[i][j] = 0.f;

    for (int k0 = 0; k0 < K; k0 += 32) {
        const float* xp = X + (size_t)(m0 + lrow) * K + k0 + ks;
        const float* wp = W + (size_t)(j0 + lrow) * K + k0 + ks;
#pragma unroll
        for (int q = 0; q < 8; ++q) {
            const int k = k0 + ks + q;
            Xs[ks + q][lrow] = (k < K) ? xp[q] : 0.f;
            Ws[ks + q][lrow] = (k < K) ? wp[q] : 0.f;
        }
        __syncthreads();
#pragma unroll 8
        for (int kk = 0; kk < 32; ++kk) {
            const float4 xv = *(const float4*)&Xs[kk][ti * 4];
            const float4 wv = *(const float4*)&Ws[kk][tj * 4];
            acc[0][0] = fmaf(xv.x, wv.x, acc[0][0]);
            acc[0][1] = fmaf(xv.x, wv.y, acc[0][1]);
            acc[0][2] = fmaf(xv.x, wv.z, acc[0][2]);
            acc[0][3] = fmaf(xv.x, wv.w, acc[0][3]);
            acc[1][0] = fmaf(xv.y, wv.x, acc[1][0]);
            acc[1][1] = fmaf(xv.y, wv.y, acc[1][1]);
            acc[1][2] = fmaf(xv.y, wv.z, acc[1][2]);
            acc[1][3] = fmaf(xv.y, wv.w, acc[1][3]);
            acc[2][0] = fmaf(xv.z, wv.x, acc[2][0]);
            acc[2][1] = fmaf(xv.z, wv.y, acc[2][1]);
            acc[2][2] = fmaf(xv.z, wv.z, acc[2][2]);
            acc[2][3] = fmaf(xv.z, wv.w, acc[2][3]);
            acc[3][0] = fmaf(xv.w, wv.x, acc[3][0]);
            acc[3][1] = fmaf(xv.w, wv.y, acc[3][1]);
            acc[3][2] = fmaf(xv.w, wv.z, acc[3][2]);
            acc[3][3] = fmaf(xv.w, wv.w, acc[3][3]);
        }
        __syncthreads();
    }
#pragma unroll
    for (int i = 0; i < 4; ++i) {
        const int m = m0 + ti * 4 + i;
#pragma unroll
        for (int j = 0; j < 4; ++j) {
            const int jj = j0 + tj * 4 + j;
            Y[(size_t)m * J + jj] = acc[i][j] + bias[jj];
        }
    }
}

// ---------------------------------------------------------------------------
// K6a: edge-parallel GATv2 logits. Wave = (4 edges, head); 16 lanes/edge,
// float4/lane. logits stored as HEADS planes of E_TOT (CSR order).
// ---------------------------------------------------------------------------
template <int FDIM, int HEADS, int WPH>
__global__ __launch_bounds__(256) void logit_kernel(
    const float* __restrict__ xl, const float* __restrict__ xr,
    const float* __restrict__ att,
    const int* __restrict__ srcs, const int* __restrict__ dsts,
    float* __restrict__ logits)   // (HEADS, E_TOT)
{
    const int wid = blockIdx.x * 4 + (threadIdx.x >> 6);
    const int h = wid / WPH;
    const int w0 = wid - h * WPH;
    const int lane = threadIdx.x & 63;
    const int e4 = lane >> 4;          // edge within group
    const int c4 = lane & 15;          // float4 slot within 64 channels

    const float4 av = *(const float4*)(att + h * 64 + c4 * 4);
    float* __restrict__ lgp = logits + (size_t)h * E_TOT;

    for (int g = w0; g < NG4; g += WPH) {
        const int e = g * 4 + e4;
        const int s = srcs[e];
        const int d = dsts[e];
        const float4 xa = *(const float4*)(xl + (size_t)s * FDIM + h * 64 + c4 * 4);
        const float4 xb = *(const float4*)(xr + (size_t)d * FDIM + h * 64 + c4 * 4);
        float u0 = xa.x + xb.x; u0 = fmaxf(u0, 0.2f * u0);
        float u1 = xa.y + xb.y; u1 = fmaxf(u1, 0.2f * u1);
        float u2 = xa.z + xb.z; u2 = fmaxf(u2, 0.2f * u2);
        float u3 = xa.w + xb.w; u3 = fmaxf(u3, 0.2f * u3);
        float p = av.x * u0 + av.y * u1 + av.z * u2 + av.w * u3;
        p += __shfl_xor(p, 1, 64);
        p += __shfl_xor(p, 2, 64);
        p += __shfl_xor(p, 4, 64);
        p += __shfl_xor(p, 8, 64);
        const float pl = __shfl(p, (lane & 3) * 16, 64);   // lane i<4 <- edge i
        if (lane < 4) lgp[g * 4 + lane] = pl;
    }
}

// ---------------------------------------------------------------------------
// K6b: per-dst softmax + aggregation. Wave = (node, head).
// Softmax cost is per-64-edge chunk, not per edge; weights+srcs via LDS;
// accumulate loop = uniform ds_read_b64 + coalesced 256B gather + fma.
// ---------------------------------------------------------------------------
__global__ __launch_bounds__(512) void gat1_agg_kernel(
    const float* __restrict__ xl, const float* __restrict__ logits,
    const float* __restrict__ bias,
    const int* __restrict__ offsets, const int* __restrict__ srcs,
    float* __restrict__ h1)
{
    __shared__ float2 wbuf[8][MAXDEG];
    const int n = blockIdx.x;
    const int h = threadIdx.x >> 6;
    const int lane = threadIdx.x & 63;
    const int base = offsets[n];
    const int deg = offsets[n + 1] - base;
    const float* __restrict__ lgp = logits + (size_t)h * E_TOT + base;

    float m = -1e30f;
    for (int c0 = 0; c0 < deg; c0 += 64) {
        float lg = (c0 + lane < deg) ? lgp[c0 + lane] : -1e30f;
#pragma unroll
        for (int o = 32; o >= 1; o >>= 1) lg = fmaxf(lg, __shfl_xor(lg, o, 64));
        m = fmaxf(m, lg);
    }
    float l = 0.f;
    for (int c0 = 0; c0 < deg; c0 += 64) {
        const bool ok = (c0 + lane) < deg;
        const float lg = ok ? lgp[c0 + lane] : -1e30f;
        const int s = ok ? srcs[base + c0 + lane] : 0;
        float ex = __expf(lg - m);
        wbuf[h][c0 + lane] = make_float2(ex, __int_as_float(s));
#pragma unroll
        for (int o = 32; o >= 1; o >>= 1) ex += __shfl_xor(ex, o, 64);
        l += ex;
    }

    float acc0 = 0.f, acc1 = 0.f;
    int e = 0;
    for (; e + 2 <= deg; e += 2) {
        const float2 w0 = wbuf[h][e];
        const float2 w1 = wbuf[h][e + 1];
        const int s0 = __float_as_int(w0.y);
        const int s1 = __float_as_int(w1.y);
        acc0 = fmaf(w0.x, xl[(size_t)s0 * F1 + h * 64 + lane], acc0);
        acc1 = fmaf(w1.x, xl[(size_t)s1 * F1 + h * 64 + lane], acc1);
    }
    if (e < deg) {
        const float2 w0 = wbuf[h][e];
        acc0 = fmaf(w0.x, xl[(size_t)__float_as_int(w0.y) * F1 + h * 64 + lane], acc0);
    }
    float v = (acc0 + acc1) / l + bias[h * 64 + lane];
    v = (v > 0.f) ? v : expm1f(v);   // ELU
    h1[(size_t)n * F1 + h * 64 + lane] = v;
}

__global__ __launch_bounds__(256) void gat2_agg_kernel(
    const float* __restrict__ xl, const float* __restrict__ logits,
    const float* __restrict__ bias,
    const int* __restrict__ offsets, const int* __restrict__ srcs,
    float* __restrict__ out)
{
    __shared__ float2 wbuf[4][MAXDEG];
    const int wv = threadIdx.x >> 6;
    const int lane = threadIdx.x & 63;
    const int n = blockIdx.x * 4 + wv;
    const int base = offsets[n];
    const int deg = offsets[n + 1] - base;
    const float* __restrict__ lgp = logits + base;

    float m = -1e30f;
    for (int c0 = 0; c0 < deg; c0 += 64) {
        float lg = (c0 + lane < deg) ? lgp[c0 + lane] : -1e30f;
#pragma unroll
        for (int o = 32; o >= 1; o >>= 1) lg = fmaxf(lg, __shfl_xor(lg, o, 64));
        m = fmaxf(m, lg);
    }
    float l = 0.f;
    for (int c0 = 0; c0 < deg; c0 += 64) {
        const bool ok = (c0 + lane) < deg;
        const float lg = ok ? lgp[c0 + lane] : -1e30f;
        const int s = ok ? srcs[base + c0 + lane] : 0;
        float ex = __expf(lg - m);
        wbuf[wv][c0 + lane] = make_float2(ex, __int_as_float(s));
#pragma unroll
        for (int o = 32; o >= 1; o >>= 1) ex += __shfl_xor(ex, o, 64);
        l += ex;
    }

    float acc0 = 0.f, acc1 = 0.f;
    int e = 0;
    for (; e + 2 <= deg; e += 2) {
        const float2 w0 = wbuf[wv][e];
        const float2 w1 = wbuf[wv][e + 1];
        acc0 = fmaf(w0.x, xl[(size_t)__float_as_int(w0.y) * F2 + lane], acc0);
        acc1 = fmaf(w1.x, xl[(size_t)__float_as_int(w1.y) * F2 + lane], acc1);
    }
    if (e < deg) {
        const float2 w0 = wbuf[wv][e];
        acc0 = fmaf(w0.x, xl[(size_t)__float_as_int(w0.y) * F2 + lane], acc0);
    }
    out[(size_t)n * F2 + lane] = (acc0 + acc1) / l + bias[lane];
}

// ---------------------------------------------------------------------------
extern "C" void kernel_launch(void* const* d_in, const int* in_sizes, int n_in,
                              void* d_out, int out_size, void* d_ws, size_t ws_size,
                              hipStream_t stream)
{
    const int*   ei    = (const int*)d_in[0];
    const float* ve    = (const float*)d_in[1];
    const float* ac    = (const float*)d_in[2];
    const float* man   = (const float*)d_in[3];
    const float* maskv = (const float*)d_in[4];
    const float* c1w   = (const float*)d_in[6];
    const float* c1b   = (const float*)d_in[7];
    const float* bn1g  = (const float*)d_in[8];
    const float* bn1b  = (const float*)d_in[9];
    const float* c2w   = (const float*)d_in[10];
    const float* c2b   = (const float*)d_in[11];
    const float* bn2g  = (const float*)d_in[12];
    const float* bn2b  = (const float*)d_in[13];
    const float* wih   = (const float*)d_in[14];
    const float* whh   = (const float*)d_in[15];
    const float* bih   = (const float*)d_in[16];
    const float* bhh   = (const float*)d_in[17];
    const float* g1wl  = (const float*)d_in[18];
    const float* g1bl  = (const float*)d_in[19];
    const float* g1wr  = (const float*)d_in[20];
    const float* g1br  = (const float*)d_in[21];
    const float* g1att = (const float*)d_in[22];
    const float* g1bias= (const float*)d_in[23];
    const float* g2wl  = (const float*)d_in[24];
    const float* g2bl  = (const float*)d_in[25];
    const float* g2wr  = (const float*)d_in[26];
    const float* g2br  = (const float*)d_in[27];
    const float* g2att = (const float*)d_in[28];
    const float* g2bias= (const float*)d_in[29];
    float* outp = (float*)d_out;

    // workspace layout (floats)
    float* ws     = (float*)d_ws;
    float* gi     = ws;                         // 584064
    float* xn     = gi     + 584064;            // 389376
    float* xl1    = xn     + 389376;            // 2555904
    float* xr1    = xl1    + 2555904;           // 2555904
    float* h1     = xr1    + 2555904;           // 2555904
    float* xl2    = h1     + 2555904;           // 319488
    float* xr2    = xl2    + 319488;            // 319488
    float* lgt1   = xr2    + 319488;            // 8 * 205056 = 1640448
    float* lgt2   = lgt1   + 1640448;           // 205056
    int* counts  = (int*)(lgt2 + 205056);       // 4992
    int* offsets = counts + NNODE;              // 4993
    int* cursor  = offsets + NNODE + 1;         // 4992
    int* srcs    = cursor + NNODE;              // 205056
    int* dsts    = srcs + E_TOT;                // 205056

    hipMemsetAsync(counts, 0, NNODE * sizeof(int), stream);

    conv_kernel<<<NBATCH, 256, 0, stream>>>(ve, ac, man, c1w, c1b, bn1g, bn1b,
                                            c2w, c2b, bn2g, bn2b, wih, bih, gi);
    gru_xn_kernel<<<(NNODE + 255) / 256, 256, 0, stream>>>(gi, whh, bhh, man, maskv, xn);

    edge_hist<<<(E_TOT + 255) / 256, 256, 0, stream>>>(ei, counts);
    scan_kernel<<<1, 256, 0, stream>>>(counts, offsets, cursor);
    edge_scatter<<<(E_TOT + 255) / 256, 256, 0, stream>>>(ei, cursor, srcs, dsts);

    gemm_kernel<78><<<dim3(NNODE / 64, 2 * (F1 / 64)), 256, 0, stream>>>(
        xn, g1wl, g1bl, g1wr, g1br, xl1, xr1, F1);

    // GAT layer 1: 8 heads, WPH=4096 -> 32768 waves -> 8192 blocks
    logit_kernel<F1, 8, 4096><<<8192, 256, 0, stream>>>(xl1, xr1, g1att, srcs, dsts, lgt1);
    gat1_agg_kernel<<<NNODE, 512, 0, stream>>>(xl1, lgt1, g1bias, offsets, srcs, h1);

    gemm_kernel<512><<<dim3(NNODE / 64, 2 * (F2 / 64)), 256, 0, stream>>>(
        h1, g2wl, g2bl, g2wr, g2br, xl2, xr2, F2);

    // GAT layer 2: 1 head, WPH=8192 -> 8192 waves -> 2048 blocks
    logit_kernel<F2, 1, 8192><<<2048, 256, 0, stream>>>(xl2, xr2, g2att, srcs, dsts, lgt2);
    gat2_agg_kernel<<<NNODE / 4, 256, 0, stream>>>(xl2, lgt2, g2bias, offsets, srcs, outp);
}

// Round 6
// 368.794 us; speedup vs baseline: 1.2490x; 1.1281x over previous
//
#include <hip/hip_runtime.h>
#include <hip/hip_bf16.h>
#include <math.h>

#define HN 39
#define WN 39
#define NBATCH 128
#define NPIX (HN * WN)          // 1521
#define NNODE (NBATCH * WN)     // 4992
#define E_RAW 200064
#define E_TOT (E_RAW + NNODE)   // 205056
#define NG4 (E_TOT / 4)         // 51264 edge-groups of 4
#define F1 512
#define F2 64
#define MAXDEG 256
#define CROWS 6                 // conv output rows per block

static __device__ __forceinline__ float nan0(float x) { return (x == x) ? x : 0.f; }
static __device__ __forceinline__ float sigmoid_f(float x) { return 1.f / (1.f + __expf(-x)); }
static __device__ __forceinline__ float tanh_f(float x) {
    float e = __expf(2.f * x);
    return 1.f - 2.f / (e + 1.f);
}

#define BN_RSQ 0.99999500003749969f   // 1/sqrt(1+1e-5)

// ---------------------------------------------------------------------------
// K1: fused nan-clean + conv1(1x1)+BN+ReLU + conv2(3x3)+BN + GRU input proj.
// R5 fix: row-stripe tiling. grid (128, 7); block owns 6 output rows with an
// 8-row halo of conv1 values in LDS (conv1 is 1x1 -> halo recompute is local).
// Was: 128 blocks total -> Occupancy 5%, VALUBusy 7.6%, 64 us (latency-bound).
// ---------------------------------------------------------------------------
__global__ __launch_bounds__(256) void conv_kernel(
    const float* __restrict__ ve, const float* __restrict__ ac, const float* __restrict__ man,
    const float* __restrict__ c1w, const float* __restrict__ c1b,
    const float* __restrict__ bn1g, const float* __restrict__ bn1b,
    const float* __restrict__ c2w, const float* __restrict__ c2b,
    const float* __restrict__ bn2g, const float* __restrict__ bn2b,
    const float* __restrict__ wih, const float* __restrict__ bih,
    float* __restrict__ gi_out)      // (B, 1521, 3)
{
    __shared__ float y1[8][(CROWS + 2) * WN + 8];
    const int b = blockIdx.x;
    const int r0 = blockIdx.y * CROWS;
    const int tid = threadIdx.x;

    // phase 1: conv1(1x1)+bn+relu for halo rows r0-1 .. r0+CROWS
    for (int p = tid; p < (CROWS + 2) * WN; p += 256) {
        const int row = p / WN;            // 0..CROWS+1
        const int hh = r0 - 1 + row;
        if (hh < 0 || hh >= HN) continue;
        const int w = p - row * WN;
        const int gidx = b * NPIX + hh * WN + w;
        const float m = nan0(man[gidx]);
        const float a = nan0(ac[gidx]);
        const float v = nan0(ve[gidx]);
#pragma unroll
        for (int c = 0; c < 8; ++c) {
            float val = c1w[c * 3 + 0] * m + c1w[c * 3 + 1] * a + c1w[c * 3 + 2] * v + c1b[c];
            val = val * (bn1g[c] * BN_RSQ) + bn1b[c];
            y1[c][p] = fmaxf(val, 0.f);
        }
    }
    __syncthreads();

    // phase 2: conv2(3x3 pad1)+bn2 + GRU input projection for rows r0..r0+CROWS-1
    for (int p = tid; p < CROWS * WN; p += 256) {
        const int h = r0 + p / WN;
        if (h >= HN) continue;
        const int w = p - (p / WN) * WN;
        float acc[16];
#pragma unroll
        for (int o = 0; o < 16; ++o) acc[o] = 0.f;
        for (int c = 0; c < 8; ++c) {
#pragma unroll
            for (int dy = 0; dy < 3; ++dy) {
                const int hh = h + dy - 1;
                if (hh < 0 || hh >= HN) continue;
                const int lrow = hh - r0 + 1;          // 0..CROWS+1
#pragma unroll
                for (int dx = 0; dx < 3; ++dx) {
                    const int ww = w + dx - 1;
                    if (ww < 0 || ww >= WN) continue;
                    const float yv = y1[c][lrow * WN + ww];
#pragma unroll
                    for (int o = 0; o < 16; ++o)
                        acc[o] = fmaf(c2w[((o * 8 + c) * 3 + dy) * 3 + dx], yv, acc[o]);
                }
            }
        }
        float gi0 = bih[0], gi1 = bih[1], gi2 = bih[2];
#pragma unroll
        for (int o = 0; o < 16; ++o) {
            const float x2 = (acc[o] + c2b[o]) * (bn2g[o] * BN_RSQ) + bn2b[o];
            gi0 = fmaf(wih[0 * 16 + o], x2, gi0);
            gi1 = fmaf(wih[1 * 16 + o], x2, gi1);
            gi2 = fmaf(wih[2 * 16 + o], x2, gi2);
        }
        const int idx = (b * NPIX + h * WN + w) * 3;
        gi_out[idx + 0] = gi0;
        gi_out[idx + 1] = gi1;
        gi_out[idx + 2] = gi2;
    }
}

// ---------------------------------------------------------------------------
// K2: fused GRU(16->1) + xn build
// ---------------------------------------------------------------------------
__global__ __launch_bounds__(256) void gru_xn_kernel(
    const float* __restrict__ gi, const float* __restrict__ whh, const float* __restrict__ bhh,
    const float* __restrict__ man, const float* __restrict__ maskv,
    float* __restrict__ xn)   // (NNODE, 78)
{
    const int idx = blockIdx.x * 256 + threadIdx.x;
    if (idx >= NNODE) return;
    const int b = idx / WN, w = idx - (idx / WN) * WN;
    const float mk = maskv[idx];
    float* __restrict__ xrow = xn + (size_t)idx * 78;

    for (int k = 0; k < HN; ++k)
        xrow[k] = nan0(man[b * NPIX + k * WN + w]) * mk;

    const float wh0 = whh[0], wh1 = whh[1], wh2 = whh[2];
    const float bh0 = bhh[0], bh1 = bhh[1], bh2 = bhh[2];
    float h = 0.f;
    for (int t = 0; t < HN; ++t) {
        const float* g = gi + ((size_t)b * NPIX + t * WN + w) * 3;
        const float g0 = g[0], g1 = g[1], g2 = g[2];
        const float r = sigmoid_f(g0 + h * wh0 + bh0);
        const float z = sigmoid_f(g1 + h * wh1 + bh1);
        const float n = tanh_f(g2 + r * (h * wh2 + bh2));
        h = (1.f - z) * n + z * h;
        xrow[HN + t] = h * mk;
    }
}

// ---------------------------------------------------------------------------
// K4: CSR build (histogram -> scan -> scatter); scatter also records dst
// ---------------------------------------------------------------------------
__global__ __launch_bounds__(256) void edge_hist(const int* __restrict__ ei, int* __restrict__ counts)
{
    const int e = blockIdx.x * 256 + threadIdx.x;
    if (e >= E_TOT) return;
    const int d = (e < E_RAW) ? ei[E_RAW + e] : (e - E_RAW);
    atomicAdd(&counts[d], 1);
}

__global__ __launch_bounds__(256) void scan_kernel(const int* __restrict__ counts,
                                                   int* __restrict__ offsets, int* __restrict__ cursor)
{
    __shared__ int sums[256];
    const int tid = threadIdx.x;
    const int start = tid * 20;
    const int end = min(start + 20, NNODE);
    int s = 0;
    for (int i = start; i < end; ++i) s += counts[i];
    sums[tid] = s;
    __syncthreads();
    for (int off = 1; off < 256; off <<= 1) {
        int v = (tid >= off) ? sums[tid - off] : 0;
        __syncthreads();
        sums[tid] += v;
        __syncthreads();
    }
    int run = (tid == 0) ? 0 : sums[tid - 1];
    for (int i = start; i < end; ++i) {
        offsets[i] = run;
        cursor[i] = run;
        run += counts[i];
    }
    if (tid == 255) offsets[NNODE] = run;
}

__global__ __launch_bounds__(256) void edge_scatter(const int* __restrict__ ei,
                                                    int* __restrict__ cursor,
                                                    int* __restrict__ srcs, int* __restrict__ dsts)
{
    const int e = blockIdx.x * 256 + threadIdx.x;
    if (e >= E_TOT) return;
    int s, d;
    if (e < E_RAW) { s = ei[e]; d = ei[E_RAW + e]; }
    else           { s = d = e - E_RAW; }
    const int pos = atomicAdd(&cursor[d], 1);
    srcs[pos] = s;
    dsts[pos] = d;
}

// ---------------------------------------------------------------------------
// K5: tiled f32 GEMM  Y = X(M,K) @ W(J,K)^T + b (unroll capped: R1 spill fix)
// ---------------------------------------------------------------------------
template <int K>
__global__ __launch_bounds__(256, 4) void gemm_kernel(
    const float* __restrict__ X,
    const float* __restrict__ Wl, const float* __restrict__ bl,
    const float* __restrict__ Wr, const float* __restrict__ br,
    float* __restrict__ Yl, float* __restrict__ Yr, int J)
{
    const int nyb = J >> 6;
    const int sel = (blockIdx.y >= nyb) ? 1 : 0;
    const int j0 = (blockIdx.y - sel * nyb) * 64;
    const float* __restrict__ W = sel ? Wr : Wl;
    const float* __restrict__ bias = sel ? br : bl;
    float* __restrict__ Y = sel ? Yr : Yl;

    __shared__ __align__(16) float Xs[32][68];
    __shared__ __align__(16) float Ws[32][68];

    const int m0 = blockIdx.x * 64;
    const int tid = threadIdx.x;
    const int ti = tid / 16, tj = tid & 15;
    const int lrow = tid >> 2;
    const int ks = (tid & 3) * 8;

    float acc[4][4];
#pragma unroll
    for (int i = 0; i < 4; ++i)
#pragma unroll
        for (int j = 0; j < 4; ++j) acc[i][j] = 0.f;

    for (int k0 = 0; k0 < K; k0 += 32) {
        const float* xp = X + (size_t)(m0 + lrow) * K + k0 + ks;
        const float* wp = W + (size_t)(j0 + lrow) * K + k0 + ks;
#pragma unroll
        for (int q = 0; q < 8; ++q) {
            const int k = k0 + ks + q;
            Xs[ks + q][lrow] = (k < K) ? xp[q] : 0.f;
            Ws[ks + q][lrow] = (k < K) ? wp[q] : 0.f;
        }
        __syncthreads();
#pragma unroll 8
        for (int kk = 0; kk < 32; ++kk) {
            const float4 xv = *(const float4*)&Xs[kk][ti * 4];
            const float4 wv = *(const float4*)&Ws[kk][tj * 4];
            acc[0][0] = fmaf(xv.x, wv.x, acc[0][0]);
            acc[0][1] = fmaf(xv.x, wv.y, acc[0][1]);
            acc[0][2] = fmaf(xv.x, wv.z, acc[0][2]);
            acc[0][3] = fmaf(xv.x, wv.w, acc[0][3]);
            acc[1][0] = fmaf(xv.y, wv.x, acc[1][0]);
            acc[1][1] = fmaf(xv.y, wv.y, acc[1][1]);
            acc[1][2] = fmaf(xv.y, wv.z, acc[1][2]);
            acc[1][3] = fmaf(xv.y, wv.w, acc[1][3]);
            acc[2][0] = fmaf(xv.z, wv.x, acc[2][0]);
            acc[2][1] = fmaf(xv.z, wv.y, acc[2][1]);
            acc[2][2] = fmaf(xv.z, wv.z, acc[2][2]);
            acc[2][3] = fmaf(xv.z, wv.w, acc[2][3]);
            acc[3][0] = fmaf(xv.w, wv.x, acc[3][0]);
            acc[3][1] = fmaf(xv.w, wv.y, acc[3][1]);
            acc[3][2] = fmaf(xv.w, wv.z, acc[3][2]);
            acc[3][3] = fmaf(xv.w, wv.w, acc[3][3]);
        }
        __syncthreads();
    }
#pragma unroll
    for (int i = 0; i < 4; ++i) {
        const int m = m0 + ti * 4 + i;
#pragma unroll
        for (int j = 0; j < 4; ++j) {
            const int jj = j0 + tj * 4 + j;
            Y[(size_t)m * J + jj] = acc[i][j] + bias[jj];
        }
    }
}

// ---------------------------------------------------------------------------
// K6a: edge-parallel GATv2 logits. Wave = (4 edges, head); 16 lanes/edge,
// float4/lane. logits stored as HEADS planes of E_TOT (CSR order).
// ---------------------------------------------------------------------------
template <int FDIM, int HEADS, int WPH>
__global__ __launch_bounds__(256) void logit_kernel(
    const float* __restrict__ xl, const float* __restrict__ xr,
    const float* __restrict__ att,
    const int* __restrict__ srcs, const int* __restrict__ dsts,
    float* __restrict__ logits)   // (HEADS, E_TOT)
{
    const int wid = blockIdx.x * 4 + (threadIdx.x >> 6);
    const int h = wid / WPH;
    const int w0 = wid - h * WPH;
    const int lane = threadIdx.x & 63;
    const int e4 = lane >> 4;          // edge within group
    const int c4 = lane & 15;          // float4 slot within 64 channels

    const float4 av = *(const float4*)(att + h * 64 + c4 * 4);
    float* __restrict__ lgp = logits + (size_t)h * E_TOT;

    for (int g = w0; g < NG4; g += WPH) {
        const int e = g * 4 + e4;
        const int s = srcs[e];
        const int d = dsts[e];
        const float4 xa = *(const float4*)(xl + (size_t)s * FDIM + h * 64 + c4 * 4);
        const float4 xb = *(const float4*)(xr + (size_t)d * FDIM + h * 64 + c4 * 4);
        float u0 = xa.x + xb.x; u0 = fmaxf(u0, 0.2f * u0);
        float u1 = xa.y + xb.y; u1 = fmaxf(u1, 0.2f * u1);
        float u2 = xa.z + xb.z; u2 = fmaxf(u2, 0.2f * u2);
        float u3 = xa.w + xb.w; u3 = fmaxf(u3, 0.2f * u3);
        float p = av.x * u0 + av.y * u1 + av.z * u2 + av.w * u3;
        p += __shfl_xor(p, 1, 64);
        p += __shfl_xor(p, 2, 64);
        p += __shfl_xor(p, 4, 64);
        p += __shfl_xor(p, 8, 64);
        const float pl = __shfl(p, (lane & 3) * 16, 64);   // lane i<4 <- edge i
        if (lane < 4) lgp[g * 4 + lane] = pl;
    }
}

// ---------------------------------------------------------------------------
// K6b: per-dst softmax + aggregation. Wave = (node, head).
// ---------------------------------------------------------------------------
__global__ __launch_bounds__(512) void gat1_agg_kernel(
    const float* __restrict__ xl, const float* __restrict__ logits,
    const float* __restrict__ bias,
    const int* __restrict__ offsets, const int* __restrict__ srcs,
    float* __restrict__ h1)
{
    __shared__ float2 wbuf[8][MAXDEG];
    const int n = blockIdx.x;
    const int h = threadIdx.x >> 6;
    const int lane = threadIdx.x & 63;
    const int base = offsets[n];
    const int deg = offsets[n + 1] - base;
    const float* __restrict__ lgp = logits + (size_t)h * E_TOT + base;

    float m = -1e30f;
    for (int c0 = 0; c0 < deg; c0 += 64) {
        float lg = (c0 + lane < deg) ? lgp[c0 + lane] : -1e30f;
#pragma unroll
        for (int o = 32; o >= 1; o >>= 1) lg = fmaxf(lg, __shfl_xor(lg, o, 64));
        m = fmaxf(m, lg);
    }
    float l = 0.f;
    for (int c0 = 0; c0 < deg; c0 += 64) {
        const bool ok = (c0 + lane) < deg;
        const float lg = ok ? lgp[c0 + lane] : -1e30f;
        const int s = ok ? srcs[base + c0 + lane] : 0;
        float ex = __expf(lg - m);
        wbuf[h][c0 + lane] = make_float2(ex, __int_as_float(s));
#pragma unroll
        for (int o = 32; o >= 1; o >>= 1) ex += __shfl_xor(ex, o, 64);
        l += ex;
    }

    float acc0 = 0.f, acc1 = 0.f;
    int e = 0;
    for (; e + 2 <= deg; e += 2) {
        const float2 w0 = wbuf[h][e];
        const float2 w1 = wbuf[h][e + 1];
        const int s0 = __float_as_int(w0.y);
        const int s1 = __float_as_int(w1.y);
        acc0 = fmaf(w0.x, xl[(size_t)s0 * F1 + h * 64 + lane], acc0);
        acc1 = fmaf(w1.x, xl[(size_t)s1 * F1 + h * 64 + lane], acc1);
    }
    if (e < deg) {
        const float2 w0 = wbuf[h][e];
        acc0 = fmaf(w0.x, xl[(size_t)__float_as_int(w0.y) * F1 + h * 64 + lane], acc0);
    }
    float v = (acc0 + acc1) / l + bias[h * 64 + lane];
    v = (v > 0.f) ? v : expm1f(v);   // ELU
    h1[(size_t)n * F1 + h * 64 + lane] = v;
}

__global__ __launch_bounds__(256) void gat2_agg_kernel(
    const float* __restrict__ xl, const float* __restrict__ logits,
    const float* __restrict__ bias,
    const int* __restrict__ offsets, const int* __restrict__ srcs,
    float* __restrict__ out)
{
    __shared__ float2 wbuf[4][MAXDEG];
    const int wv = threadIdx.x >> 6;
    const int lane = threadIdx.x & 63;
    const int n = blockIdx.x * 4 + wv;
    const int base = offsets[n];
    const int deg = offsets[n + 1] - base;
    const float* __restrict__ lgp = logits + base;

    float m = -1e30f;
    for (int c0 = 0; c0 < deg; c0 += 64) {
        float lg = (c0 + lane < deg) ? lgp[c0 + lane] : -1e30f;
#pragma unroll
        for (int o = 32; o >= 1; o >>= 1) lg = fmaxf(lg, __shfl_xor(lg, o, 64));
        m = fmaxf(m, lg);
    }
    float l = 0.f;
    for (int c0 = 0; c0 < deg; c0 += 64) {
        const bool ok = (c0 + lane) < deg;
        const float lg = ok ? lgp[c0 + lane] : -1e30f;
        const int s = ok ? srcs[base + c0 + lane] : 0;
        float ex = __expf(lg - m);
        wbuf[wv][c0 + lane] = make_float2(ex, __int_as_float(s));
#pragma unroll
        for (int o = 32; o >= 1; o >>= 1) ex += __shfl_xor(ex, o, 64);
        l += ex;
    }

    float acc0 = 0.f, acc1 = 0.f;
    int e = 0;
    for (; e + 2 <= deg; e += 2) {
        const float2 w0 = wbuf[wv][e];
        const float2 w1 = wbuf[wv][e + 1];
        acc0 = fmaf(w0.x, xl[(size_t)__float_as_int(w0.y) * F2 + lane], acc0);
        acc1 = fmaf(w1.x, xl[(size_t)__float_as_int(w1.y) * F2 + lane], acc1);
    }
    if (e < deg) {
        const float2 w0 = wbuf[wv][e];
        acc0 = fmaf(w0.x, xl[(size_t)__float_as_int(w0.y) * F2 + lane], acc0);
    }
    out[(size_t)n * F2 + lane] = (acc0 + acc1) / l + bias[lane];
}

// ---------------------------------------------------------------------------
extern "C" void kernel_launch(void* const* d_in, const int* in_sizes, int n_in,
                              void* d_out, int out_size, void* d_ws, size_t ws_size,
                              hipStream_t stream)
{
    const int*   ei    = (const int*)d_in[0];
    const float* ve    = (const float*)d_in[1];
    const float* ac    = (const float*)d_in[2];
    const float* man   = (const float*)d_in[3];
    const float* maskv = (const float*)d_in[4];
    const float* c1w   = (const float*)d_in[6];
    const float* c1b   = (const float*)d_in[7];
    const float* bn1g  = (const float*)d_in[8];
    const float* bn1b  = (const float*)d_in[9];
    const float* c2w   = (const float*)d_in[10];
    const float* c2b   = (const float*)d_in[11];
    const float* bn2g  = (const float*)d_in[12];
    const float* bn2b  = (const float*)d_in[13];
    const float* wih   = (const float*)d_in[14];
    const float* whh   = (const float*)d_in[15];
    const float* bih   = (const float*)d_in[16];
    const float* bhh   = (const float*)d_in[17];
    const float* g1wl  = (const float*)d_in[18];
    const float* g1bl  = (const float*)d_in[19];
    const float* g1wr  = (const float*)d_in[20];
    const float* g1br  = (const float*)d_in[21];
    const float* g1att = (const float*)d_in[22];
    const float* g1bias= (const float*)d_in[23];
    const float* g2wl  = (const float*)d_in[24];
    const float* g2bl  = (const float*)d_in[25];
    const float* g2wr  = (const float*)d_in[26];
    const float* g2br  = (const float*)d_in[27];
    const float* g2att = (const float*)d_in[28];
    const float* g2bias= (const float*)d_in[29];
    float* outp = (float*)d_out;

    // workspace layout (floats)
    float* ws     = (float*)d_ws;
    float* gi     = ws;                         // 584064
    float* xn     = gi     + 584064;            // 389376
    float* xl1    = xn     + 389376;            // 2555904
    float* xr1    = xl1    + 2555904;           // 2555904
    float* h1     = xr1    + 2555904;           // 2555904
    float* xl2    = h1     + 2555904;           // 319488
    float* xr2    = xl2    + 319488;            // 319488
    float* lgt1   = xr2    + 319488;            // 8 * 205056 = 1640448
    float* lgt2   = lgt1   + 1640448;           // 205056
    int* counts  = (int*)(lgt2 + 205056);       // 4992
    int* offsets = counts + NNODE;              // 4993
    int* cursor  = offsets + NNODE + 1;         // 4992
    int* srcs    = cursor + NNODE;              // 205056
    int* dsts    = srcs + E_TOT;                // 205056

    hipMemsetAsync(counts, 0, NNODE * sizeof(int), stream);

    conv_kernel<<<dim3(NBATCH, (HN + CROWS - 1) / CROWS), 256, 0, stream>>>(
        ve, ac, man, c1w, c1b, bn1g, bn1b, c2w, c2b, bn2g, bn2b, wih, bih, gi);
    gru_xn_kernel<<<(NNODE + 255) / 256, 256, 0, stream>>>(gi, whh, bhh, man, maskv, xn);

    edge_hist<<<(E_TOT + 255) / 256, 256, 0, stream>>>(ei, counts);
    scan_kernel<<<1, 256, 0, stream>>>(counts, offsets, cursor);
    edge_scatter<<<(E_TOT + 255) / 256, 256, 0, stream>>>(ei, cursor, srcs, dsts);

    gemm_kernel<78><<<dim3(NNODE / 64, 2 * (F1 / 64)), 256, 0, stream>>>(
        xn, g1wl, g1bl, g1wr, g1br, xl1, xr1, F1);

    // GAT layer 1: 8 heads, WPH=4096 -> 32768 waves -> 8192 blocks
    logit_kernel<F1, 8, 4096><<<8192, 256, 0, stream>>>(xl1, xr1, g1att, srcs, dsts, lgt1);
    gat1_agg_kernel<<<NNODE, 512, 0, stream>>>(xl1, lgt1, g1bias, offsets, srcs, h1);

    gemm_kernel<512><<<dim3(NNODE / 64, 2 * (F2 / 64)), 256, 0, stream>>>(
        h1, g2wl, g2bl, g2wr, g2br, xl2, xr2, F2);

    // GAT layer 2: 1 head, WPH=8192 -> 8192 waves -> 2048 blocks
    logit_kernel<F2, 1, 8192><<<2048, 256, 0, stream>>>(xl2, xr2, g2att, srcs, dsts, lgt2);
    gat2_agg_kernel<<<NNODE / 4, 256, 0, stream>>>(xl2, lgt2, g2bias, offsets, srcs, outp);
}